// Round 9
// baseline (803.751 us; speedup 1.0000x reference)
//
#include <hip/hip_runtime.h>

#define N_NODES 100000
#define N_EDGES 1600000
#define NFEAT 64
#define NCLASS 64
#define NGROUPS (N_NODES / 16)   // 6250 16-node MFMA groups, exact

// coarse bins (pass 1): 8 dst-ranges of 12500 nodes
#define CGRP 8
#define CRANGE 12500
#define CAP1 204800              // per coarse bucket (mean 200K, +11 sigma)
// fine bins (pass 2): 511 parts of 196 nodes
#define PARTS 511
#define NPP 196
#define CAP2 3712                // per fine bucket (mean 3131, +10 sigma)

typedef __attribute__((ext_vector_type(8))) short bf16x8;   // 8 bf16 = 4 VGPRs
typedef __attribute__((ext_vector_type(4))) float f32x4;

__device__ inline unsigned short f2bf(float f) {   // round-to-nearest-even
    union { float f; unsigned u; } v; v.f = f;
    unsigned u = v.u + 0x7fffu + ((v.u >> 16) & 1u);
    return (unsigned short)(u >> 16);
}
__device__ inline float bf2f(unsigned short s) {
    union { unsigned u; float f; } v; v.u = ((unsigned)s) << 16;
    return v.f;
}

// ---------------------------------------------------------------------------
__global__ void zero_int_kernel(int* __restrict__ p, int n) {
    int i = blockIdx.x * blockDim.x + threadIdx.x;
    int stride = gridDim.x * blockDim.x;
    for (; i < n; i += stride) p[i] = 0;
}

// ---------------------------------------------------------------------------
// x -> bf16 cast (one streaming pass)
// ---------------------------------------------------------------------------
__global__ void x2bf_kernel(const float4* __restrict__ x4,
                            ushort4* __restrict__ xb4) {
    int i = blockIdx.x * blockDim.x + threadIdx.x;
    const int n4 = N_NODES * NFEAT / 4;
    int stride = gridDim.x * blockDim.x;
    for (; i < n4; i += stride) {
        float4 v = x4[i];
        ushort4 o;
        o.x = f2bf(v.x); o.y = f2bf(v.y); o.z = f2bf(v.z); o.w = f2bf(v.w);
        xb4[i] = o;
    }
}

// ---------------------------------------------------------------------------
// Weight prep: Wcat[c][0:64]=bf16(W_rel[c][:]), Wcat[c][64:128]=bf16(W_root[c][:])
// ---------------------------------------------------------------------------
__global__ __launch_bounds__(256) void wprep_kernel(const float* __restrict__ W_rel,
                                                    const float* __restrict__ W_root,
                                                    unsigned short* __restrict__ Wcat) {
    int i = blockIdx.x * blockDim.x + threadIdx.x;
    if (i >= NCLASS * 128) return;
    int c = i >> 7, k = i & 127;
    float v = (k < 64) ? W_rel[c * 64 + k] : W_root[c * 64 + (k - 64)];
    Wcat[i] = f2bf(v);
}

// ---------------------------------------------------------------------------
// Pass 1: LDS-bin edges into 8 coarse dst-ranges; flush contiguous ~256B
// chunks per bucket (full-line writes, no cross-XCD read-modify-write).
// cursor1 padded 16 ints apart (64B) to avoid hot-line atomic serialization.
// ---------------------------------------------------------------------------
__global__ __launch_bounds__(256) void bin1_kernel(const int* __restrict__ src,
                                                   const int* __restrict__ dst,
                                                   int* __restrict__ cursor1,
                                                   uint2* __restrict__ staging1) {
    __shared__ uint2 buck[CGRP][256];
    __shared__ int bcnt[CGRP];
    __shared__ int bbase[CGRP];
    const int tid = threadIdx.x;
    const int lane = tid & 63;
    const int w = tid >> 6;
    const int nbatch = (N_EDGES + 255) / 256;   // 6250
    for (int batch = blockIdx.x; batch < nbatch; batch += gridDim.x) {
        if (tid < CGRP) bcnt[tid] = 0;
        __syncthreads();
        int e = batch * 256 + tid;
        if (e < N_EDGES) {
            unsigned d = (unsigned)dst[e];
            unsigned s = (unsigned)src[e];
            unsigned p = d / (unsigned)CRANGE;
            int pos = atomicAdd(&bcnt[p], 1);
            buck[p][pos] = make_uint2(d, s);
        }
        __syncthreads();
        if (tid < CGRP) bbase[tid] = atomicAdd(&cursor1[tid * 16], bcnt[tid]);
        __syncthreads();
        for (int b = w; b < CGRP; b += 4) {
            int c = bcnt[b];
            int gb = bbase[b];
            for (int i = lane; i < c; i += 64) {
                int o = gb + i;
                if (o < CAP1) staging1[(size_t)b * CAP1 + o] = buck[b][i];
            }
        }
        __syncthreads();
    }
}

// ---------------------------------------------------------------------------
// Pass 2: group g = blockIdx&7 (one XCD) consumes ONLY coarse bucket g
// (no redundant reads), repacks to (dlocal<<17 | src) in fine buckets of
// 196 nodes. Scattered 4B writes + cursor atomics stay in that XCD's L2.
// ---------------------------------------------------------------------------
__global__ __launch_bounds__(256) void bin2_kernel(const uint2* __restrict__ staging1,
                                                   const int* __restrict__ cursor1,
                                                   int* __restrict__ cursor2,
                                                   unsigned* __restrict__ staging2) {
    const int g  = blockIdx.x & (CGRP - 1);
    const int gb = blockIdx.x >> 3;
    const int nb = gridDim.x >> 3;
    const int cnt = min(cursor1[g * 16], CAP1);
    const uint2* sg = staging1 + (size_t)g * CAP1;
    for (int i = gb * 256 + (int)threadIdx.x; i < cnt; i += nb * 256) {
        uint2 v = sg[i];
        unsigned d = v.x, s = v.y;
        unsigned p  = d / (unsigned)NPP;
        unsigned dl = d - p * (unsigned)NPP;
        int pos = atomicAdd(&cursor2[p * 16], 1);
        if (pos < CAP2) staging2[(size_t)p * CAP2 + pos] = (dl << 17) | s;
    }
}

// ---------------------------------------------------------------------------
// Aggregate: one 1024-thread block per fine part. fp32 agg tile (196x64,
// 50KB) in LDS; per entry: uniform staging read -> 128B x_bf row gather ->
// ds_add_f32. Unroll-8 keeps 16 memory ops in flight per wave.
// ---------------------------------------------------------------------------
__global__ __launch_bounds__(1024) void agg_kernel(const unsigned short* __restrict__ x_bf,
                                                   const unsigned* __restrict__ staging2,
                                                   const int* __restrict__ cursor2,
                                                   unsigned short* __restrict__ agg_bf) {
    __shared__ float aggL[NPP * 64];   // 50176 B
    const int p = blockIdx.x;
    const int tid = threadIdx.x;
    const int lane = tid & 63;
    const int w = tid >> 6;            // 0..15
    for (int i = tid; i < NPP * 64; i += 1024) aggL[i] = 0.f;
    __syncthreads();
    const int cnt = min(cursor2[p * 16], CAP2);
    const unsigned* base = staging2 + (size_t)p * CAP2;
    int i = w;
    for (; i + 112 < cnt; i += 128) {          // 8 entries per wave per iter
        unsigned v[8]; float xv[8]; unsigned dl[8];
        #pragma unroll
        for (int j = 0; j < 8; ++j) v[j] = base[i + 16 * j];
        #pragma unroll
        for (int j = 0; j < 8; ++j) {
            unsigned s = v[j] & 0x1FFFFu; dl[j] = v[j] >> 17;
            xv[j] = bf2f(x_bf[(size_t)s * 64 + lane]);
        }
        #pragma unroll
        for (int j = 0; j < 8; ++j) atomicAdd(&aggL[dl[j] * 64 + lane], xv[j]);
    }
    for (; i < cnt; i += 16) {
        unsigned v = base[i];
        unsigned s = v & 0x1FFFFu, dl = v >> 17;
        atomicAdd(&aggL[dl * 64 + lane], bf2f(x_bf[(size_t)s * 64 + lane]));
    }
    __syncthreads();
    for (int r = w; r < NPP; r += 16) {
        int node = p * NPP + r;
        if (node < N_NODES)
            agg_bf[(size_t)node * 64 + lane] = f2bf(aggL[r * 64 + lane]);
    }
}

// ---------------------------------------------------------------------------
// MFMA transform (round-8 proven): out[n][c] = relu(agg.Wrel + x.Wroot + b)
// A: kk=0,1 from agg_bf, kk=2,3 from x_bf. m89-verified fragment layouts.
// ---------------------------------------------------------------------------
__global__ __launch_bounds__(256, 2) void transform_mfma_kernel(
    const unsigned short* __restrict__ agg_bf,  // [N][64] bf16
    const unsigned short* __restrict__ x_bf,    // [N][64] bf16
    const unsigned short* __restrict__ Wcat,    // [64][128] bf16
    const float* __restrict__ b_rel,
    float* __restrict__ out) {
    const int lane = threadIdx.x & 63;
    const int lr = lane & 15;
    const int lh = lane >> 4;

    bf16x8 bfr[4][4];
    #pragma unroll
    for (int cg = 0; cg < 4; ++cg)
        #pragma unroll
        for (int kk = 0; kk < 4; ++kk)
            bfr[cg][kk] = *(const bf16x8*)(Wcat + (cg * 16 + lr) * 128 + kk * 32 + lh * 8);

    float bias[4];
    #pragma unroll
    for (int cg = 0; cg < 4; ++cg) bias[cg] = b_rel[cg * 16 + lr];

    int wid = (blockIdx.x * blockDim.x + threadIdx.x) >> 6;
    int nw  = (gridDim.x * blockDim.x) >> 6;

    for (int g = wid; g < NGROUPS; g += nw) {
        const unsigned short* Aa = agg_bf + (size_t)(g * 16 + lr) * 64;
        const unsigned short* Ax = x_bf   + (size_t)(g * 16 + lr) * 64;
        bf16x8 afr[4];
        #pragma unroll
        for (int kk = 0; kk < 2; ++kk) {
            afr[kk]     = *(const bf16x8*)(Aa + kk * 32 + lh * 8);
            afr[kk + 2] = *(const bf16x8*)(Ax + kk * 32 + lh * 8);
        }
        #pragma unroll
        for (int cg = 0; cg < 4; ++cg) {
            f32x4 acc = {0.f, 0.f, 0.f, 0.f};
            #pragma unroll
            for (int kk = 0; kk < 4; ++kk)
                acc = __builtin_amdgcn_mfma_f32_16x16x32_bf16(afr[kk], bfr[cg][kk], acc, 0, 0, 0);
            #pragma unroll
            for (int r = 0; r < 4; ++r)
                out[(size_t)(g * 16 + lh * 4 + r) * 64 + cg * 16 + lr] =
                    fmaxf(acc[r] + bias[cg], 0.f);
        }
    }
}

// ---------------------------------------------------------------------------
// Fallback path (needs no workspace): atomic scatter + fp32 transform
// ---------------------------------------------------------------------------
__global__ void zero_kernel(float4* __restrict__ p, int n4) {
    int i = blockIdx.x * blockDim.x + threadIdx.x;
    int stride = gridDim.x * blockDim.x;
    for (; i < n4; i += stride) p[i] = make_float4(0.f, 0.f, 0.f, 0.f);
}

__global__ void scatter_kernel(const float4* __restrict__ x4,
                               const int* __restrict__ src,
                               const int* __restrict__ dst,
                               float* __restrict__ agg) {
    int idx = blockIdx.x * blockDim.x + threadIdx.x;
    const int total = N_EDGES * 16;
    int stride = gridDim.x * blockDim.x;
    for (; idx < total; idx += stride) {
        int e = idx >> 4;
        int q = idx & 15;
        int s = src[e];
        int d = dst[e];
        float4 v = x4[s * 16 + q];
        float* base = agg + d * 64 + q * 4;
        unsafeAtomicAdd(base + 0, v.x);
        unsafeAtomicAdd(base + 1, v.y);
        unsafeAtomicAdd(base + 2, v.z);
        unsafeAtomicAdd(base + 3, v.w);
    }
}

__global__ __launch_bounds__(256, 1) void transform3_kernel(
    const float* __restrict__ x,
    const float* __restrict__ W_rel,
    const float* __restrict__ b_rel,
    const float* __restrict__ W_root,
    float* __restrict__ agg_out) {
    const int lane = threadIdx.x & 63;
    float4 wr[16], wo[16];
    const float4* Wr4 = (const float4*)W_rel;
    const float4* Wo4 = (const float4*)W_root;
    #pragma unroll
    for (int i = 0; i < 16; ++i) {
        float4 a = Wr4[lane * 16 + i];
        float4 b = Wo4[lane * 16 + i];
        asm volatile("" : "+v"(a.x), "+v"(a.y), "+v"(a.z), "+v"(a.w));
        asm volatile("" : "+v"(b.x), "+v"(b.y), "+v"(b.z), "+v"(b.w));
        wr[i] = a;
        wo[i] = b;
    }
    const float bias = b_rel[lane];
    int gwave = (blockIdx.x * blockDim.x + threadIdx.x) >> 6;
    int nwaves = (gridDim.x * blockDim.x) >> 6;
    for (int node = gwave; node < N_NODES; node += nwaves) {
        const float4* ar4 = (const float4*)(agg_out + (size_t)node * 64);
        const float4* xr4 = (const float4*)(x + (size_t)node * 64);
        float acc = bias;
        #pragma unroll
        for (int i = 0; i < 16; ++i) {
            float4 a = ar4[i];
            float4 v = xr4[i];
            acc += a.x * wr[i].x + a.y * wr[i].y + a.z * wr[i].z + a.w * wr[i].w;
            acc += v.x * wo[i].x + v.y * wo[i].y + v.z * wo[i].z + v.w * wo[i].w;
        }
        agg_out[(size_t)node * 64 + lane] = fmaxf(acc, 0.f);
    }
}

extern "C" void kernel_launch(void* const* d_in, const int* in_sizes, int n_in,
                              void* d_out, int out_size, void* d_ws, size_t ws_size,
                              hipStream_t stream) {
    const float* x      = (const float*)d_in[0];
    const int*   adj    = (const int*)d_in[1];   // delivered as int32 [2][N_EDGES]
    const float* W_rel  = (const float*)d_in[2];
    const float* b_rel  = (const float*)d_in[3];
    const float* W_root = (const float*)d_in[4];
    float*       out    = (float*)d_out;

    const int* src = adj;
    const int* dst = adj + N_EDGES;

    // workspace layout (128B-aligned sections):
    //   cursor1: ints [0,128)            (8 counters, 64B apart)
    //   cursor2: ints [128, 128+511*16)  (511 counters, 64B apart)
    //   staging2: ints [8320, 8320+511*3712)
    //   x_bf / agg_bf / Wcat: bf16 after that
    // staging1 (8 x 204800 uint2 = 13.1 MB) lives in d_out (25.6 MB),
    // consumed by bin2 BEFORE transform writes d_out.
    const size_t CUR_INTS  = 128 + (size_t)PARTS * 16;          // 8304
    const size_t STG2_OFF  = 8320;                              // ints, 128B aligned
    const size_t STG2_INTS = (size_t)PARTS * CAP2;              // 1,896,832
    const size_t bf_base   = (STG2_OFF + STG2_INTS) * sizeof(int); // 7,620,608 B
    const size_t row_elems = (size_t)N_NODES * 64;
    const size_t ws_needed = bf_base + (2 * row_elems + (size_t)NCLASS * 128) * sizeof(unsigned short);

    if (ws_size >= ws_needed) {
        int*      cursor1  = (int*)d_ws;
        int*      cursor2  = cursor1 + 128;
        unsigned* staging2 = (unsigned*)d_ws + STG2_OFF;
        unsigned short* x_bf   = (unsigned short*)((char*)d_ws + bf_base);
        unsigned short* agg_bf = x_bf + row_elems;
        unsigned short* Wcat   = agg_bf + row_elems;
        uint2* staging1 = (uint2*)d_out;

        zero_int_kernel<<<64, 256, 0, stream>>>(cursor1, (int)CUR_INTS);
        x2bf_kernel<<<2048, 256, 0, stream>>>((const float4*)x, (ushort4*)x_bf);
        wprep_kernel<<<(NCLASS * 128 + 255) / 256, 256, 0, stream>>>(W_rel, W_root, Wcat);
        bin1_kernel<<<1024, 256, 0, stream>>>(src, dst, cursor1, staging1);
        bin2_kernel<<<2048, 256, 0, stream>>>(staging1, cursor1, cursor2, staging2);
        agg_kernel<<<PARTS, 1024, 0, stream>>>(x_bf, staging2, cursor2, agg_bf);
        transform_mfma_kernel<<<1024, 256, 0, stream>>>(agg_bf, x_bf, Wcat, b_rel, out);
    } else {
        zero_kernel<<<2048, 256, 0, stream>>>((float4*)out, (N_NODES * NFEAT) / 4);
        scatter_kernel<<<4096, 256, 0, stream>>>((const float4*)x, src, dst, out);
        transform3_kernel<<<1024, 256, 0, stream>>>(x, W_rel, b_rel, W_root, out);
    }
}

// Round 10
// 354.703 us; speedup vs baseline: 2.2660x; 2.2660x over previous
//
#include <hip/hip_runtime.h>

#define N_NODES 100000
#define N_EDGES 1600000
#define NFEAT 64
#define NCLASS 64
#define NGROUPS (N_NODES / 16)   // 6250 16-node MFMA groups, exact

// coarse bins: 8 dst-ranges of 12500 nodes (one per XCD)
#define CGRP 8
#define CRANGE 12500
#define CAP1 204800              // per coarse bucket (mean 200K, +10.7 sigma)

typedef __attribute__((ext_vector_type(8))) short bf16x8;   // 8 bf16 = 4 VGPRs
typedef __attribute__((ext_vector_type(4))) float f32x4;

__device__ inline unsigned short f2bf(float f) {   // round-to-nearest-even
    union { float f; unsigned u; } v; v.f = f;
    unsigned u = v.u + 0x7fffu + ((v.u >> 16) & 1u);
    return (unsigned short)(u >> 16);
}
__device__ inline float bf2f(unsigned short s) {
    union { unsigned u; float f; } v; v.u = ((unsigned)s) << 16;
    return v.f;
}

// ---------------------------------------------------------------------------
__global__ void zero_int_kernel(int* __restrict__ p, int n) {
    int i = blockIdx.x * blockDim.x + threadIdx.x;
    int stride = gridDim.x * blockDim.x;
    for (; i < n; i += stride) p[i] = 0;
}

// ---------------------------------------------------------------------------
// x -> bf16 cast (one streaming pass; halves all downstream gather traffic)
// ---------------------------------------------------------------------------
__global__ void x2bf_kernel(const float4* __restrict__ x4,
                            ushort4* __restrict__ xb4) {
    int i = blockIdx.x * blockDim.x + threadIdx.x;
    const int n4 = N_NODES * NFEAT / 4;
    int stride = gridDim.x * blockDim.x;
    for (; i < n4; i += stride) {
        float4 v = x4[i];
        ushort4 o;
        o.x = f2bf(v.x); o.y = f2bf(v.y); o.z = f2bf(v.z); o.w = f2bf(v.w);
        xb4[i] = o;
    }
}

// ---------------------------------------------------------------------------
// Weight prep: Wcat[c][0:64]=bf16(W_rel[c][:]), Wcat[c][64:128]=bf16(W_root[c][:])
// ---------------------------------------------------------------------------
__global__ __launch_bounds__(256) void wprep_kernel(const float* __restrict__ W_rel,
                                                    const float* __restrict__ W_root,
                                                    unsigned short* __restrict__ Wcat) {
    int i = blockIdx.x * blockDim.x + threadIdx.x;
    if (i >= NCLASS * 128) return;
    int c = i >> 7, k = i & 127;
    float v = (k < 64) ? W_rel[c * 64 + k] : W_root[c * 64 + (k - 64)];
    Wcat[i] = f2bf(v);
}

// ---------------------------------------------------------------------------
// Pass 1 (round-9 proven): LDS-bin edges into 8 coarse dst-ranges; flush
// contiguous chunks per bucket (coalesced 8B-entry writes, single adj read).
// cursor1 entries 64B apart to avoid hot-line atomic serialization.
// ---------------------------------------------------------------------------
__global__ __launch_bounds__(256) void bin1_kernel(const int* __restrict__ src,
                                                   const int* __restrict__ dst,
                                                   int* __restrict__ cursor1,
                                                   uint2* __restrict__ staging1) {
    __shared__ uint2 buck[CGRP][256];
    __shared__ int bcnt[CGRP];
    __shared__ int bbase[CGRP];
    const int tid = threadIdx.x;
    const int lane = tid & 63;
    const int w = tid >> 6;
    const int nbatch = (N_EDGES + 255) / 256;   // 6250
    for (int batch = blockIdx.x; batch < nbatch; batch += gridDim.x) {
        if (tid < CGRP) bcnt[tid] = 0;
        __syncthreads();
        int e = batch * 256 + tid;
        if (e < N_EDGES) {
            unsigned d = (unsigned)dst[e];
            unsigned s = (unsigned)src[e];
            unsigned p = d / (unsigned)CRANGE;
            int pos = atomicAdd(&bcnt[p], 1);
            buck[p][pos] = make_uint2(d, s);
        }
        __syncthreads();
        if (tid < CGRP) bbase[tid] = atomicAdd(&cursor1[tid * 16], bcnt[tid]);
        __syncthreads();
        for (int b = w; b < CGRP; b += 4) {
            int c = bcnt[b];
            int gb = bbase[b];
            for (int i = lane; i < c; i += 64) {
                int o = gb + i;
                if (o < CAP1) staging1[(size_t)b * CAP1 + o] = buck[b][i];
            }
        }
        __syncthreads();
    }
}

// ---------------------------------------------------------------------------
// hist2: group g=blockIdx&7 counts ONLY coarse bucket g (no redundant read);
// its deg slice (50KB) stays XCD-local.
// ---------------------------------------------------------------------------
__global__ __launch_bounds__(256) void hist2_kernel(const uint2* __restrict__ staging1,
                                                    const int* __restrict__ cursor1,
                                                    int* __restrict__ deg) {
    const int g  = blockIdx.x & (CGRP - 1);
    const int gb = blockIdx.x >> 3;
    const int nb = gridDim.x >> 3;
    const int cnt = min(cursor1[g * 16], CAP1);
    const uint2* sg = staging1 + (size_t)g * CAP1;
    for (int i = gb * 256 + (int)threadIdx.x; i < cnt; i += nb * 256)
        atomicAdd(&deg[sg[i].x], 1);
}

// ---- multi-block exclusive scan of deg[0..N_NODES) -> offs, cursor ----
#define SCAN_CHUNK 512
#define SCAN_NBLK ((N_NODES + SCAN_CHUNK - 1) / SCAN_CHUNK)   // 196

__global__ __launch_bounds__(256) void scan1_kernel(const int* __restrict__ deg,
                                                    int* __restrict__ blocksum) {
    __shared__ int part[256];
    int b = blockIdx.x, t = threadIdx.x;
    int i0 = b * SCAN_CHUNK + t * 2;
    int s = 0;
    if (i0 < N_NODES)     s += deg[i0];
    if (i0 + 1 < N_NODES) s += deg[i0 + 1];
    part[t] = s;
    __syncthreads();
    for (int off = 128; off > 0; off >>= 1) {
        if (t < off) part[t] += part[t + off];
        __syncthreads();
    }
    if (t == 0) blocksum[b] = part[0];
}

__global__ __launch_bounds__(256) void scan2_kernel(const int* __restrict__ blocksum,
                                                    int* __restrict__ blockoff,
                                                    int* __restrict__ offs) {
    __shared__ int part[256];
    int t = threadIdx.x;
    int v = (t < SCAN_NBLK) ? blocksum[t] : 0;
    part[t] = v;
    __syncthreads();
    for (int off = 1; off < 256; off <<= 1) {
        int u = (t >= off) ? part[t - off] : 0;
        __syncthreads();
        part[t] += u;
        __syncthreads();
    }
    if (t < SCAN_NBLK) blockoff[t] = part[t] - v;   // exclusive
    if (t == 0) offs[N_NODES] = part[255];
}

__global__ __launch_bounds__(256) void scan3_kernel(const int* __restrict__ deg,
                                                    const int* __restrict__ blockoff,
                                                    int* __restrict__ offs,
                                                    int* __restrict__ cursor) {
    __shared__ int part[256];
    int b = blockIdx.x, t = threadIdx.x;
    int i0 = b * SCAN_CHUNK + t * 2;
    int d0 = (i0 < N_NODES) ? deg[i0] : 0;
    int d1 = (i0 + 1 < N_NODES) ? deg[i0 + 1] : 0;
    int p = d0 + d1;
    part[t] = p;
    __syncthreads();
    for (int off = 1; off < 256; off <<= 1) {
        int u = (t >= off) ? part[t - off] : 0;
        __syncthreads();
        part[t] += u;
        __syncthreads();
    }
    int base = blockoff[b] + part[t] - p;
    if (i0 < N_NODES)     { offs[i0] = base;           cursor[i0] = base; }
    if (i0 + 1 < N_NODES) { offs[i0 + 1] = base + d0;  cursor[i0 + 1] = base + d0; }
}

// ---------------------------------------------------------------------------
// fill2: group g=blockIdx&7 fills CSR srclist ONLY from coarse bucket g.
// cursor slice (50KB) + srclist slice (~1.6MB) stay in one XCD's L2 ->
// each srclist line written once to HBM (vs round-8 fill_part's 72MB).
// ---------------------------------------------------------------------------
__global__ __launch_bounds__(256) void fill2_kernel(const uint2* __restrict__ staging1,
                                                    const int* __restrict__ cursor1,
                                                    int* __restrict__ cursor,
                                                    int* __restrict__ srclist) {
    const int g  = blockIdx.x & (CGRP - 1);
    const int gb = blockIdx.x >> 3;
    const int nb = gridDim.x >> 3;
    const int cnt = min(cursor1[g * 16], CAP1);
    const uint2* sg = staging1 + (size_t)g * CAP1;
    for (int i = gb * 256 + (int)threadIdx.x; i < cnt; i += nb * 256) {
        uint2 v = sg[i];
        int p = atomicAdd(&cursor[v.x], 1);
        srclist[p] = (int)v.y;
    }
}

// ---------------------------------------------------------------------------
// Gather aggregation over bf16 rows (round-8 proven): one wave per node.
// ---------------------------------------------------------------------------
__global__ __launch_bounds__(256) void gather_bf_kernel(
    const unsigned short* __restrict__ x_bf,
    const int* __restrict__ offs,
    const int* __restrict__ srclist,
    unsigned short* __restrict__ agg_bf) {
    int wave = (blockIdx.x * blockDim.x + threadIdx.x) >> 6;
    int lane = threadIdx.x & 63;
    if (wave >= N_NODES) return;
    int beg = offs[wave];
    int end = offs[wave + 1];
    float acc = 0.f;
    int j = beg;
    for (; j + 4 <= end; j += 4) {
        int s0 = srclist[j + 0];
        int s1 = srclist[j + 1];
        int s2 = srclist[j + 2];
        int s3 = srclist[j + 3];
        unsigned short v0 = x_bf[(size_t)s0 * 64 + lane];
        unsigned short v1 = x_bf[(size_t)s1 * 64 + lane];
        unsigned short v2 = x_bf[(size_t)s2 * 64 + lane];
        unsigned short v3 = x_bf[(size_t)s3 * 64 + lane];
        acc += bf2f(v0); acc += bf2f(v1); acc += bf2f(v2); acc += bf2f(v3);
    }
    for (; j < end; ++j) acc += bf2f(x_bf[(size_t)srclist[j] * 64 + lane]);
    agg_bf[(size_t)wave * 64 + lane] = f2bf(acc);
}

// ---------------------------------------------------------------------------
// MFMA transform (round-8 proven): out[n][c] = relu(agg.Wrel + x.Wroot + b)
// A: kk=0,1 from agg_bf, kk=2,3 from x_bf. m89-verified fragment layouts.
// ---------------------------------------------------------------------------
__global__ __launch_bounds__(256, 2) void transform_mfma_kernel(
    const unsigned short* __restrict__ agg_bf,  // [N][64] bf16
    const unsigned short* __restrict__ x_bf,    // [N][64] bf16
    const unsigned short* __restrict__ Wcat,    // [64][128] bf16
    const float* __restrict__ b_rel,
    float* __restrict__ out) {
    const int lane = threadIdx.x & 63;
    const int lr = lane & 15;
    const int lh = lane >> 4;

    bf16x8 bfr[4][4];
    #pragma unroll
    for (int cg = 0; cg < 4; ++cg)
        #pragma unroll
        for (int kk = 0; kk < 4; ++kk)
            bfr[cg][kk] = *(const bf16x8*)(Wcat + (cg * 16 + lr) * 128 + kk * 32 + lh * 8);

    float bias[4];
    #pragma unroll
    for (int cg = 0; cg < 4; ++cg) bias[cg] = b_rel[cg * 16 + lr];

    int wid = (blockIdx.x * blockDim.x + threadIdx.x) >> 6;
    int nw  = (gridDim.x * blockDim.x) >> 6;

    for (int g = wid; g < NGROUPS; g += nw) {
        const unsigned short* Aa = agg_bf + (size_t)(g * 16 + lr) * 64;
        const unsigned short* Ax = x_bf   + (size_t)(g * 16 + lr) * 64;
        bf16x8 afr[4];
        #pragma unroll
        for (int kk = 0; kk < 2; ++kk) {
            afr[kk]     = *(const bf16x8*)(Aa + kk * 32 + lh * 8);
            afr[kk + 2] = *(const bf16x8*)(Ax + kk * 32 + lh * 8);
        }
        #pragma unroll
        for (int cg = 0; cg < 4; ++cg) {
            f32x4 acc = {0.f, 0.f, 0.f, 0.f};
            #pragma unroll
            for (int kk = 0; kk < 4; ++kk)
                acc = __builtin_amdgcn_mfma_f32_16x16x32_bf16(afr[kk], bfr[cg][kk], acc, 0, 0, 0);
            #pragma unroll
            for (int r = 0; r < 4; ++r)
                out[(size_t)(g * 16 + lh * 4 + r) * 64 + cg * 16 + lr] =
                    fmaxf(acc[r] + bias[cg], 0.f);
        }
    }
}

// ---------------------------------------------------------------------------
// Fallback path (needs no workspace): atomic scatter + fp32 transform
// ---------------------------------------------------------------------------
__global__ void zero_kernel(float4* __restrict__ p, int n4) {
    int i = blockIdx.x * blockDim.x + threadIdx.x;
    int stride = gridDim.x * blockDim.x;
    for (; i < n4; i += stride) p[i] = make_float4(0.f, 0.f, 0.f, 0.f);
}

__global__ void scatter_kernel(const float4* __restrict__ x4,
                               const int* __restrict__ src,
                               const int* __restrict__ dst,
                               float* __restrict__ agg) {
    int idx = blockIdx.x * blockDim.x + threadIdx.x;
    const int total = N_EDGES * 16;
    int stride = gridDim.x * blockDim.x;
    for (; idx < total; idx += stride) {
        int e = idx >> 4;
        int q = idx & 15;
        int s = src[e];
        int d = dst[e];
        float4 v = x4[s * 16 + q];
        float* base = agg + d * 64 + q * 4;
        unsafeAtomicAdd(base + 0, v.x);
        unsafeAtomicAdd(base + 1, v.y);
        unsafeAtomicAdd(base + 2, v.z);
        unsafeAtomicAdd(base + 3, v.w);
    }
}

__global__ __launch_bounds__(256, 1) void transform3_kernel(
    const float* __restrict__ x,
    const float* __restrict__ W_rel,
    const float* __restrict__ b_rel,
    const float* __restrict__ W_root,
    float* __restrict__ agg_out) {
    const int lane = threadIdx.x & 63;
    float4 wr[16], wo[16];
    const float4* Wr4 = (const float4*)W_rel;
    const float4* Wo4 = (const float4*)W_root;
    #pragma unroll
    for (int i = 0; i < 16; ++i) {
        float4 a = Wr4[lane * 16 + i];
        float4 b = Wo4[lane * 16 + i];
        asm volatile("" : "+v"(a.x), "+v"(a.y), "+v"(a.z), "+v"(a.w));
        asm volatile("" : "+v"(b.x), "+v"(b.y), "+v"(b.z), "+v"(b.w));
        wr[i] = a;
        wo[i] = b;
    }
    const float bias = b_rel[lane];
    int gwave = (blockIdx.x * blockDim.x + threadIdx.x) >> 6;
    int nwaves = (gridDim.x * blockDim.x) >> 6;
    for (int node = gwave; node < N_NODES; node += nwaves) {
        const float4* ar4 = (const float4*)(agg_out + (size_t)node * 64);
        const float4* xr4 = (const float4*)(x + (size_t)node * 64);
        float acc = bias;
        #pragma unroll
        for (int i = 0; i < 16; ++i) {
            float4 a = ar4[i];
            float4 v = xr4[i];
            acc += a.x * wr[i].x + a.y * wr[i].y + a.z * wr[i].z + a.w * wr[i].w;
            acc += v.x * wo[i].x + v.y * wo[i].y + v.z * wo[i].z + v.w * wo[i].w;
        }
        agg_out[(size_t)node * 64 + lane] = fmaxf(acc, 0.f);
    }
}

extern "C" void kernel_launch(void* const* d_in, const int* in_sizes, int n_in,
                              void* d_out, int out_size, void* d_ws, size_t ws_size,
                              hipStream_t stream) {
    const float* x      = (const float*)d_in[0];
    const int*   adj    = (const int*)d_in[1];   // delivered as int32 [2][N_EDGES]
    const float* W_rel  = (const float*)d_in[2];
    const float* b_rel  = (const float*)d_in[3];
    const float* W_root = (const float*)d_in[4];
    float*       out    = (float*)d_out;

    const int* src = adj;
    const int* dst = adj + N_EDGES;

    // workspace layout (ints first, then bf16):
    //   cursor1[128] | deg[NPAD] | offs[NPAD] | cursor[NPAD]
    //   | blocksum[BPAD] | blockoff[BPAD] | srclist[N_EDGES]
    //   | x_bf | agg_bf | Wcat   (bf16)
    // staging1 (8 x 204800 uint2 = 13.1MB) lives in d_out (25.6MB),
    // fully consumed by hist2/fill2 BEFORE transform writes d_out.
    const size_t NPAD = 100032;                 // >= N_NODES+1, multiple of 64
    const size_t BPAD = 256;
    const size_t n_ints = 128 + 3 * NPAD + 2 * BPAD + (size_t)N_EDGES;
    const size_t row_elems = (size_t)N_NODES * 64;
    const size_t bf_base = ((n_ints * sizeof(int)) + 127) & ~(size_t)127;
    const size_t ws_needed = bf_base +
        (2 * row_elems + (size_t)NCLASS * 128) * sizeof(unsigned short);

    if (ws_size >= ws_needed) {
        int* cursor1  = (int*)d_ws;
        int* deg      = cursor1 + 128;
        int* offs     = deg + NPAD;
        int* cursor   = offs + NPAD;
        int* blocksum = cursor + NPAD;
        int* blockoff = blocksum + BPAD;
        int* srclist  = blockoff + BPAD;
        unsigned short* x_bf   = (unsigned short*)((char*)d_ws + bf_base);
        unsigned short* agg_bf = x_bf + row_elems;
        unsigned short* Wcat   = agg_bf + row_elems;
        uint2* staging1 = (uint2*)d_out;

        zero_int_kernel<<<128, 256, 0, stream>>>(cursor1, 128 + N_NODES); // cursor1+deg
        x2bf_kernel<<<2048, 256, 0, stream>>>((const float4*)x, (ushort4*)x_bf);
        wprep_kernel<<<(NCLASS * 128 + 255) / 256, 256, 0, stream>>>(W_rel, W_root, Wcat);
        bin1_kernel<<<1024, 256, 0, stream>>>(src, dst, cursor1, staging1);
        hist2_kernel<<<2048, 256, 0, stream>>>(staging1, cursor1, deg);
        scan1_kernel<<<SCAN_NBLK, 256, 0, stream>>>(deg, blocksum);
        scan2_kernel<<<1, 256, 0, stream>>>(blocksum, blockoff, offs);
        scan3_kernel<<<SCAN_NBLK, 256, 0, stream>>>(deg, blockoff, offs, cursor);
        fill2_kernel<<<2048, 256, 0, stream>>>(staging1, cursor1, cursor, srclist);
        gather_bf_kernel<<<(N_NODES * 64 + 255) / 256, 256, 0, stream>>>(x_bf, offs, srclist, agg_bf);
        transform_mfma_kernel<<<1024, 256, 0, stream>>>(agg_bf, x_bf, Wcat, b_rel, out);
    } else {
        zero_kernel<<<2048, 256, 0, stream>>>((float4*)out, (N_NODES * NFEAT) / 4);
        scatter_kernel<<<4096, 256, 0, stream>>>((const float4*)x, src, dst, out);
        transform3_kernel<<<1024, 256, 0, stream>>>(x, W_rel, b_rel, W_root, out);
    }
}

// Round 11
// 234.402 us; speedup vs baseline: 3.4289x; 1.5132x over previous
//
#include <hip/hip_runtime.h>

#define N_NODES 100000
#define N_EDGES 1600000
#define NFEAT 64
#define NCLASS 64
#define NGROUPS (N_NODES / 16)   // 6250 16-node MFMA groups, exact

// coarse bins: 8 dst-ranges of 12500 nodes (one per XCD group)
#define CGRP 8
#define CRANGE 12500
// bin1: static per-block ownership, no global allocation
#define BIN_BLOCKS 512
#define EPB (N_EDGES / BIN_BLOCKS)   // 3125 edges per block, exact
#define CAPB 576                     // per (block,bucket) cap: mean 390.6, +10 sigma

typedef __attribute__((ext_vector_type(8))) short bf16x8;   // 8 bf16 = 4 VGPRs
typedef __attribute__((ext_vector_type(4))) float f32x4;

__device__ inline unsigned short f2bf(float f) {   // round-to-nearest-even
    union { float f; unsigned u; } v; v.f = f;
    unsigned u = v.u + 0x7fffu + ((v.u >> 16) & 1u);
    return (unsigned short)(u >> 16);
}
__device__ inline float bf2f(unsigned short s) {
    union { unsigned u; float f; } v; v.u = ((unsigned)s) << 16;
    return v.f;
}

// ---------------------------------------------------------------------------
__global__ void zero_int_kernel(int* __restrict__ p, int n) {
    int i = blockIdx.x * blockDim.x + threadIdx.x;
    int stride = gridDim.x * blockDim.x;
    for (; i < n; i += stride) p[i] = 0;
}

// ---------------------------------------------------------------------------
// x -> bf16 cast (one streaming pass; halves all downstream gather traffic)
// ---------------------------------------------------------------------------
__global__ void x2bf_kernel(const float4* __restrict__ x4,
                            ushort4* __restrict__ xb4) {
    int i = blockIdx.x * blockDim.x + threadIdx.x;
    const int n4 = N_NODES * NFEAT / 4;
    int stride = gridDim.x * blockDim.x;
    for (; i < n4; i += stride) {
        float4 v = x4[i];
        ushort4 o;
        o.x = f2bf(v.x); o.y = f2bf(v.y); o.z = f2bf(v.z); o.w = f2bf(v.w);
        xb4[i] = o;
    }
}

// ---------------------------------------------------------------------------
// Weight prep: Wcat[c][0:64]=bf16(W_rel[c][:]), Wcat[c][64:128]=bf16(W_root[c][:])
// ---------------------------------------------------------------------------
__global__ __launch_bounds__(256) void wprep_kernel(const float* __restrict__ W_rel,
                                                    const float* __restrict__ W_root,
                                                    unsigned short* __restrict__ Wcat) {
    int i = blockIdx.x * blockDim.x + threadIdx.x;
    if (i >= NCLASS * 128) return;
    int c = i >> 7, k = i & 127;
    float v = (k < 64) ? W_rel[c * 64 + k] : W_root[c * 64 + (k - 64)];
    Wcat[i] = f2bf(v);
}

// ---------------------------------------------------------------------------
// bin1 v3: block blk owns edges [blk*EPB, (blk+1)*EPB) and a PRIVATE staging
// region of CGRP x CAPB entries -> zero global allocation atomics (round-10
// lesson: the hot cursor1 atomic chain cost ~100us). Per-bucket running
// offsets in LDS. deg histogram folded in as fire-and-forget atomics
// (no return value -> no latency dependency). Final counts written once.
// ---------------------------------------------------------------------------
__global__ __launch_bounds__(256) void bin1_kernel(const int* __restrict__ src,
                                                   const int* __restrict__ dst,
                                                   int* __restrict__ deg,
                                                   int* __restrict__ counts,
                                                   uint2* __restrict__ staging1) {
    __shared__ uint2 buck[CGRP][256];
    __shared__ int bcnt[CGRP];
    __shared__ int boff[CGRP];
    const int blk = blockIdx.x;
    const int tid = threadIdx.x;
    const int lane = tid & 63;
    const int w = tid >> 6;
    if (tid < CGRP) boff[tid] = 0;
    const int e0 = blk * EPB;
    for (int batch = 0; batch < EPB; batch += 256) {
        if (tid < CGRP) bcnt[tid] = 0;
        __syncthreads();
        int rel = batch + tid;
        if (rel < EPB) {
            int e = e0 + rel;
            unsigned d = (unsigned)dst[e];
            unsigned s = (unsigned)src[e];
            unsigned p = d / (unsigned)CRANGE;
            int pos = atomicAdd(&bcnt[p], 1);   // LDS, ~32-way mean: cheap
            buck[p][pos] = make_uint2(d, s);
            atomicAdd(&deg[d], 1);              // fire-and-forget histogram
        }
        __syncthreads();
        for (int b = w; b < CGRP; b += 4) {     // wave w flushes buckets w, w+4
            int c = bcnt[b];
            int off = boff[b];
            uint2* dp = staging1 + ((size_t)(blk * CGRP + b)) * CAPB + off;
            for (int i = lane; i < c; i += 64)
                if (off + i < CAPB) dp[i] = buck[b][i];
        }
        __syncthreads();
        if (tid < CGRP) boff[tid] = min(boff[tid] + bcnt[tid], CAPB);
        __syncthreads();
    }
    if (tid < CGRP) counts[blk * CGRP + tid] = boff[tid];
}

// ---- multi-block exclusive scan of deg[0..N_NODES) -> offs, cursor ----
#define SCAN_CHUNK 512
#define SCAN_NBLK ((N_NODES + SCAN_CHUNK - 1) / SCAN_CHUNK)   // 196

__global__ __launch_bounds__(256) void scan1_kernel(const int* __restrict__ deg,
                                                    int* __restrict__ blocksum) {
    __shared__ int part[256];
    int b = blockIdx.x, t = threadIdx.x;
    int i0 = b * SCAN_CHUNK + t * 2;
    int s = 0;
    if (i0 < N_NODES)     s += deg[i0];
    if (i0 + 1 < N_NODES) s += deg[i0 + 1];
    part[t] = s;
    __syncthreads();
    for (int off = 128; off > 0; off >>= 1) {
        if (t < off) part[t] += part[t + off];
        __syncthreads();
    }
    if (t == 0) blocksum[b] = part[0];
}

__global__ __launch_bounds__(256) void scan2_kernel(const int* __restrict__ blocksum,
                                                    int* __restrict__ blockoff,
                                                    int* __restrict__ offs) {
    __shared__ int part[256];
    int t = threadIdx.x;
    int v = (t < SCAN_NBLK) ? blocksum[t] : 0;
    part[t] = v;
    __syncthreads();
    for (int off = 1; off < 256; off <<= 1) {
        int u = (t >= off) ? part[t - off] : 0;
        __syncthreads();
        part[t] += u;
        __syncthreads();
    }
    if (t < SCAN_NBLK) blockoff[t] = part[t] - v;   // exclusive
    if (t == 0) offs[N_NODES] = part[255];
}

__global__ __launch_bounds__(256) void scan3_kernel(const int* __restrict__ deg,
                                                    const int* __restrict__ blockoff,
                                                    int* __restrict__ offs,
                                                    int* __restrict__ cursor) {
    __shared__ int part[256];
    int b = blockIdx.x, t = threadIdx.x;
    int i0 = b * SCAN_CHUNK + t * 2;
    int d0 = (i0 < N_NODES) ? deg[i0] : 0;
    int d1 = (i0 + 1 < N_NODES) ? deg[i0 + 1] : 0;
    int p = d0 + d1;
    part[t] = p;
    __syncthreads();
    for (int off = 1; off < 256; off <<= 1) {
        int u = (t >= off) ? part[t - off] : 0;
        __syncthreads();
        part[t] += u;
        __syncthreads();
    }
    int base = blockoff[b] + part[t] - p;
    if (i0 < N_NODES)     { offs[i0] = base;           cursor[i0] = base; }
    if (i0 + 1 < N_NODES) { offs[i0 + 1] = base + d0;  cursor[i0 + 1] = base + d0; }
}

// ---------------------------------------------------------------------------
// fill3: group g=blockIdx&7 fills CSR srclist from its bucket's 512 private
// segments (counts-guided, coalesced reads). cursor slice (50KB) + srclist
// slice (~1.6MB) stay in one XCD's L2.
// ---------------------------------------------------------------------------
__global__ __launch_bounds__(256) void fill3_kernel(const uint2* __restrict__ staging1,
                                                    const int* __restrict__ counts,
                                                    int* __restrict__ cursor,
                                                    int* __restrict__ srclist) {
    const int g  = blockIdx.x & (CGRP - 1);
    const int gb = blockIdx.x >> 3;
    const int nb = gridDim.x >> 3;
    for (int r = gb; r < BIN_BLOCKS; r += nb) {
        const int cnt = counts[r * CGRP + g];
        const uint2* sg = staging1 + ((size_t)(r * CGRP + g)) * CAPB;
        for (int i = threadIdx.x; i < cnt; i += 256) {
            uint2 v = sg[i];
            int p = atomicAdd(&cursor[v.x], 1);
            srclist[p] = (int)v.y;
        }
    }
}

// ---------------------------------------------------------------------------
// Gather aggregation over bf16 rows (round-8 proven): one wave per node.
// ---------------------------------------------------------------------------
__global__ __launch_bounds__(256) void gather_bf_kernel(
    const unsigned short* __restrict__ x_bf,
    const int* __restrict__ offs,
    const int* __restrict__ srclist,
    unsigned short* __restrict__ agg_bf) {
    int wave = (blockIdx.x * blockDim.x + threadIdx.x) >> 6;
    int lane = threadIdx.x & 63;
    if (wave >= N_NODES) return;
    int beg = offs[wave];
    int end = offs[wave + 1];
    float acc = 0.f;
    int j = beg;
    for (; j + 4 <= end; j += 4) {
        int s0 = srclist[j + 0];
        int s1 = srclist[j + 1];
        int s2 = srclist[j + 2];
        int s3 = srclist[j + 3];
        unsigned short v0 = x_bf[(size_t)s0 * 64 + lane];
        unsigned short v1 = x_bf[(size_t)s1 * 64 + lane];
        unsigned short v2 = x_bf[(size_t)s2 * 64 + lane];
        unsigned short v3 = x_bf[(size_t)s3 * 64 + lane];
        acc += bf2f(v0); acc += bf2f(v1); acc += bf2f(v2); acc += bf2f(v3);
    }
    for (; j < end; ++j) acc += bf2f(x_bf[(size_t)srclist[j] * 64 + lane]);
    agg_bf[(size_t)wave * 64 + lane] = f2bf(acc);
}

// ---------------------------------------------------------------------------
// MFMA transform (round-8 proven): out[n][c] = relu(agg.Wrel + x.Wroot + b)
// A: kk=0,1 from agg_bf, kk=2,3 from x_bf. m89-verified fragment layouts.
// ---------------------------------------------------------------------------
__global__ __launch_bounds__(256, 2) void transform_mfma_kernel(
    const unsigned short* __restrict__ agg_bf,  // [N][64] bf16
    const unsigned short* __restrict__ x_bf,    // [N][64] bf16
    const unsigned short* __restrict__ Wcat,    // [64][128] bf16
    const float* __restrict__ b_rel,
    float* __restrict__ out) {
    const int lane = threadIdx.x & 63;
    const int lr = lane & 15;
    const int lh = lane >> 4;

    bf16x8 bfr[4][4];
    #pragma unroll
    for (int cg = 0; cg < 4; ++cg)
        #pragma unroll
        for (int kk = 0; kk < 4; ++kk)
            bfr[cg][kk] = *(const bf16x8*)(Wcat + (cg * 16 + lr) * 128 + kk * 32 + lh * 8);

    float bias[4];
    #pragma unroll
    for (int cg = 0; cg < 4; ++cg) bias[cg] = b_rel[cg * 16 + lr];

    int wid = (blockIdx.x * blockDim.x + threadIdx.x) >> 6;
    int nw  = (gridDim.x * blockDim.x) >> 6;

    for (int g = wid; g < NGROUPS; g += nw) {
        const unsigned short* Aa = agg_bf + (size_t)(g * 16 + lr) * 64;
        const unsigned short* Ax = x_bf   + (size_t)(g * 16 + lr) * 64;
        bf16x8 afr[4];
        #pragma unroll
        for (int kk = 0; kk < 2; ++kk) {
            afr[kk]     = *(const bf16x8*)(Aa + kk * 32 + lh * 8);
            afr[kk + 2] = *(const bf16x8*)(Ax + kk * 32 + lh * 8);
        }
        #pragma unroll
        for (int cg = 0; cg < 4; ++cg) {
            f32x4 acc = {0.f, 0.f, 0.f, 0.f};
            #pragma unroll
            for (int kk = 0; kk < 4; ++kk)
                acc = __builtin_amdgcn_mfma_f32_16x16x32_bf16(afr[kk], bfr[cg][kk], acc, 0, 0, 0);
            #pragma unroll
            for (int r = 0; r < 4; ++r)
                out[(size_t)(g * 16 + lh * 4 + r) * 64 + cg * 16 + lr] =
                    fmaxf(acc[r] + bias[cg], 0.f);
        }
    }
}

// ---------------------------------------------------------------------------
// Fallback path (needs no workspace): atomic scatter + fp32 transform
// ---------------------------------------------------------------------------
__global__ void zero_kernel(float4* __restrict__ p, int n4) {
    int i = blockIdx.x * blockDim.x + threadIdx.x;
    int stride = gridDim.x * blockDim.x;
    for (; i < n4; i += stride) p[i] = make_float4(0.f, 0.f, 0.f, 0.f);
}

__global__ void scatter_kernel(const float4* __restrict__ x4,
                               const int* __restrict__ src,
                               const int* __restrict__ dst,
                               float* __restrict__ agg) {
    int idx = blockIdx.x * blockDim.x + threadIdx.x;
    const int total = N_EDGES * 16;
    int stride = gridDim.x * blockDim.x;
    for (; idx < total; idx += stride) {
        int e = idx >> 4;
        int q = idx & 15;
        int s = src[e];
        int d = dst[e];
        float4 v = x4[s * 16 + q];
        float* base = agg + d * 64 + q * 4;
        unsafeAtomicAdd(base + 0, v.x);
        unsafeAtomicAdd(base + 1, v.y);
        unsafeAtomicAdd(base + 2, v.z);
        unsafeAtomicAdd(base + 3, v.w);
    }
}

__global__ __launch_bounds__(256, 1) void transform3_kernel(
    const float* __restrict__ x,
    const float* __restrict__ W_rel,
    const float* __restrict__ b_rel,
    const float* __restrict__ W_root,
    float* __restrict__ agg_out) {
    const int lane = threadIdx.x & 63;
    float4 wr[16], wo[16];
    const float4* Wr4 = (const float4*)W_rel;
    const float4* Wo4 = (const float4*)W_root;
    #pragma unroll
    for (int i = 0; i < 16; ++i) {
        float4 a = Wr4[lane * 16 + i];
        float4 b = Wo4[lane * 16 + i];
        asm volatile("" : "+v"(a.x), "+v"(a.y), "+v"(a.z), "+v"(a.w));
        asm volatile("" : "+v"(b.x), "+v"(b.y), "+v"(b.z), "+v"(b.w));
        wr[i] = a;
        wo[i] = b;
    }
    const float bias = b_rel[lane];
    int gwave = (blockIdx.x * blockDim.x + threadIdx.x) >> 6;
    int nwaves = (gridDim.x * blockDim.x) >> 6;
    for (int node = gwave; node < N_NODES; node += nwaves) {
        const float4* ar4 = (const float4*)(agg_out + (size_t)node * 64);
        const float4* xr4 = (const float4*)(x + (size_t)node * 64);
        float acc = bias;
        #pragma unroll
        for (int i = 0; i < 16; ++i) {
            float4 a = ar4[i];
            float4 v = xr4[i];
            acc += a.x * wr[i].x + a.y * wr[i].y + a.z * wr[i].z + a.w * wr[i].w;
            acc += v.x * wo[i].x + v.y * wo[i].y + v.z * wo[i].z + v.w * wo[i].w;
        }
        agg_out[(size_t)node * 64 + lane] = fmaxf(acc, 0.f);
    }
}

extern "C" void kernel_launch(void* const* d_in, const int* in_sizes, int n_in,
                              void* d_out, int out_size, void* d_ws, size_t ws_size,
                              hipStream_t stream) {
    const float* x      = (const float*)d_in[0];
    const int*   adj    = (const int*)d_in[1];   // delivered as int32 [2][N_EDGES]
    const float* W_rel  = (const float*)d_in[2];
    const float* b_rel  = (const float*)d_in[3];
    const float* W_root = (const float*)d_in[4];
    float*       out    = (float*)d_out;

    const int* src = adj;
    const int* dst = adj + N_EDGES;

    // workspace layout (ints first, then bf16):
    //   counts[CPAD] | deg[NPAD] | offs[NPAD] | cursor[NPAD]
    //   | blocksum[BPAD] | blockoff[BPAD] | srclist[N_EDGES]
    //   | x_bf | agg_bf | Wcat   (bf16)
    // staging1 (512 blk x 8 buckets x 576 uint2 = 18.9MB) lives in d_out
    // (25.6MB), fully consumed by fill3 BEFORE transform writes d_out.
    const size_t CPAD = 4160;                   // >= BIN_BLOCKS*CGRP (4096)
    const size_t NPAD = 100032;                 // >= N_NODES+1, multiple of 64
    const size_t BPAD = 256;
    const size_t n_ints = CPAD + 3 * NPAD + 2 * BPAD + (size_t)N_EDGES;
    const size_t row_elems = (size_t)N_NODES * 64;
    const size_t bf_base = ((n_ints * sizeof(int)) + 127) & ~(size_t)127;
    const size_t ws_needed = bf_base +
        (2 * row_elems + (size_t)NCLASS * 128) * sizeof(unsigned short);

    if (ws_size >= ws_needed) {
        int* counts   = (int*)d_ws;
        int* deg      = counts + CPAD;
        int* offs     = deg + NPAD;
        int* cursor   = offs + NPAD;
        int* blocksum = cursor + NPAD;
        int* blockoff = blocksum + BPAD;
        int* srclist  = blockoff + BPAD;
        unsigned short* x_bf   = (unsigned short*)((char*)d_ws + bf_base);
        unsigned short* agg_bf = x_bf + row_elems;
        unsigned short* Wcat   = agg_bf + row_elems;
        uint2* staging1 = (uint2*)d_out;

        zero_int_kernel<<<128, 256, 0, stream>>>(deg, N_NODES);
        x2bf_kernel<<<2048, 256, 0, stream>>>((const float4*)x, (ushort4*)x_bf);
        wprep_kernel<<<(NCLASS * 128 + 255) / 256, 256, 0, stream>>>(W_rel, W_root, Wcat);
        bin1_kernel<<<BIN_BLOCKS, 256, 0, stream>>>(src, dst, deg, counts, staging1);
        scan1_kernel<<<SCAN_NBLK, 256, 0, stream>>>(deg, blocksum);
        scan2_kernel<<<1, 256, 0, stream>>>(blocksum, blockoff, offs);
        scan3_kernel<<<SCAN_NBLK, 256, 0, stream>>>(deg, blockoff, offs, cursor);
        fill3_kernel<<<2048, 256, 0, stream>>>(staging1, counts, cursor, srclist);
        gather_bf_kernel<<<(N_NODES * 64 + 255) / 256, 256, 0, stream>>>(x_bf, offs, srclist, agg_bf);
        transform_mfma_kernel<<<1024, 256, 0, stream>>>(agg_bf, x_bf, Wcat, b_rel, out);
    } else {
        zero_kernel<<<2048, 256, 0, stream>>>((float4*)out, (N_NODES * NFEAT) / 4);
        scatter_kernel<<<4096, 256, 0, stream>>>((const float4*)x, src, dst, out);
        transform3_kernel<<<1024, 256, 0, stream>>>(x, W_rel, b_rel, W_root, out);
    }
}

// Round 12
// 233.357 us; speedup vs baseline: 3.4443x; 1.0045x over previous
//
#include <hip/hip_runtime.h>

#define N_NODES 100000
#define N_EDGES 1600000
#define NFEAT 64
#define NCLASS 64
#define NGROUPS (N_NODES / 16)   // 6250 16-node MFMA groups, exact

// coarse bins: 8 dst-ranges of 12500 nodes
#define CGRP 8
#define CRANGE 12500
// bin1: static per-block ownership, ballot-positioned
#define BIN_BLOCKS 1250
#define EPB 1280                 // 5 batches of 256, exact: 1250*1280 = 1.6M
#define CAPB 256                 // per (block,bucket) cap: mean 160, +8 sigma

typedef __attribute__((ext_vector_type(8))) short bf16x8;   // 8 bf16 = 4 VGPRs
typedef __attribute__((ext_vector_type(4))) float f32x4;

__device__ inline unsigned short f2bf(float f) {   // round-to-nearest-even
    union { float f; unsigned u; } v; v.f = f;
    unsigned u = v.u + 0x7fffu + ((v.u >> 16) & 1u);
    return (unsigned short)(u >> 16);
}
__device__ inline float bf2f(unsigned short s) {
    union { unsigned u; float f; } v; v.u = ((unsigned)s) << 16;
    return v.f;
}

// ---------------------------------------------------------------------------
__global__ void zero_int_kernel(int* __restrict__ p, int n) {
    int i = blockIdx.x * blockDim.x + threadIdx.x;
    int stride = gridDim.x * blockDim.x;
    for (; i < n; i += stride) p[i] = 0;
}

// ---------------------------------------------------------------------------
// prep: x -> bf16 cast (vectorized) + Wcat bf16 concat, one launch.
// ---------------------------------------------------------------------------
#define X_ITEMS (N_NODES * NFEAT / 4)          // 1,600,000 float4->ushort4
#define W_ITEMS (NCLASS * 128)                 // 8,192 scalar
__global__ void prep_kernel(const float4* __restrict__ x4,
                            ushort4* __restrict__ xb4,
                            const float* __restrict__ W_rel,
                            const float* __restrict__ W_root,
                            unsigned short* __restrict__ Wcat) {
    int i = blockIdx.x * blockDim.x + threadIdx.x;
    int stride = gridDim.x * blockDim.x;
    for (; i < X_ITEMS + W_ITEMS; i += stride) {
        if (i < X_ITEMS) {
            float4 v = x4[i];
            ushort4 o;
            o.x = f2bf(v.x); o.y = f2bf(v.y); o.z = f2bf(v.z); o.w = f2bf(v.w);
            xb4[i] = o;
        } else {
            int j = i - X_ITEMS;
            int c = j >> 7, k = j & 127;
            float v = (k < 64) ? W_rel[c * 64 + k] : W_root[c * 64 + (k - 64)];
            Wcat[j] = f2bf(v);
        }
    }
}

// ---------------------------------------------------------------------------
// bin1 v4: static per-block staging (round-11) + ballot positioning + more
// blocks. Per batch: 8 ballots give each lane its in-wave bucket prefix;
// 8 LDS atomics per WAVE (lanes 0-7) allocate per-wave bases (round-11 had
// 64 serialized per-thread atomic-returns). 1250 blocks (~5/CU) hide the
// serial-batch latency that capped round-11 at 20% occupancy.
// deg histogram folded in fire-and-forget.
// ---------------------------------------------------------------------------
__global__ __launch_bounds__(256) void bin1_kernel(const int* __restrict__ src,
                                                   const int* __restrict__ dst,
                                                   int* __restrict__ deg,
                                                   int* __restrict__ counts,
                                                   uint2* __restrict__ staging1) {
    __shared__ uint2 buck[CGRP][256];
    __shared__ int bcnt[CGRP];
    __shared__ int boff[CGRP];
    const int blk = blockIdx.x;
    const int tid = threadIdx.x;
    const int lane = tid & 63;
    const int w = tid >> 6;
    if (tid < CGRP) boff[tid] = 0;
    const int e0 = blk * EPB;
    #pragma unroll 1
    for (int batch = 0; batch < EPB; batch += 256) {
        if (tid < CGRP) bcnt[tid] = 0;
        __syncthreads();
        int e = e0 + batch + tid;            // always in range: EPB = 5*256
        unsigned d = (unsigned)dst[e];
        unsigned s = (unsigned)src[e];
        unsigned p = d / (unsigned)CRANGE;
        unsigned long long below = (1ull << lane) - 1ull;
        int myprefix = 0, lanecnt = 0;
        #pragma unroll
        for (int b = 0; b < CGRP; ++b) {
            unsigned long long m = __ballot(p == (unsigned)b);
            if (lane == b) lanecnt = (int)__popcll(m);
            if (p == (unsigned)b) myprefix = (int)__popcll(m & below);
        }
        int wbase = 0;
        if (lane < CGRP) wbase = atomicAdd(&bcnt[lane], lanecnt);
        int base = __shfl(wbase, (int)p);
        buck[p][base + myprefix] = make_uint2(d, s);
        atomicAdd(&deg[d], 1);               // fire-and-forget histogram
        __syncthreads();
        for (int b = w; b < CGRP; b += 4) {  // wave w flushes buckets w, w+4
            int c = bcnt[b];
            int off = boff[b];
            uint2* dp = staging1 + ((size_t)(blk * CGRP + b)) * CAPB + off;
            for (int i = lane; i < c; i += 64)
                if (off + i < CAPB) dp[i] = buck[b][i];
        }
        __syncthreads();
        if (tid < CGRP) boff[tid] = min(boff[tid] + bcnt[tid], CAPB);
        __syncthreads();
    }
    if (tid < CGRP) counts[blk * CGRP + tid] = boff[tid];
}

// ---- multi-block exclusive scan of deg[0..N_NODES) -> offs, cursor ----
#define SCAN_CHUNK 512
#define SCAN_NBLK ((N_NODES + SCAN_CHUNK - 1) / SCAN_CHUNK)   // 196

__global__ __launch_bounds__(256) void scan1_kernel(const int* __restrict__ deg,
                                                    int* __restrict__ blocksum) {
    __shared__ int part[256];
    int b = blockIdx.x, t = threadIdx.x;
    int i0 = b * SCAN_CHUNK + t * 2;
    int s = 0;
    if (i0 < N_NODES)     s += deg[i0];
    if (i0 + 1 < N_NODES) s += deg[i0 + 1];
    part[t] = s;
    __syncthreads();
    for (int off = 128; off > 0; off >>= 1) {
        if (t < off) part[t] += part[t + off];
        __syncthreads();
    }
    if (t == 0) blocksum[b] = part[0];
}

__global__ __launch_bounds__(256) void scan2_kernel(const int* __restrict__ blocksum,
                                                    int* __restrict__ blockoff,
                                                    int* __restrict__ offs) {
    __shared__ int part[256];
    int t = threadIdx.x;
    int v = (t < SCAN_NBLK) ? blocksum[t] : 0;
    part[t] = v;
    __syncthreads();
    for (int off = 1; off < 256; off <<= 1) {
        int u = (t >= off) ? part[t - off] : 0;
        __syncthreads();
        part[t] += u;
        __syncthreads();
    }
    if (t < SCAN_NBLK) blockoff[t] = part[t] - v;   // exclusive
    if (t == 0) offs[N_NODES] = part[255];
}

__global__ __launch_bounds__(256) void scan3_kernel(const int* __restrict__ deg,
                                                    const int* __restrict__ blockoff,
                                                    int* __restrict__ offs,
                                                    int* __restrict__ cursor) {
    __shared__ int part[256];
    int b = blockIdx.x, t = threadIdx.x;
    int i0 = b * SCAN_CHUNK + t * 2;
    int d0 = (i0 < N_NODES) ? deg[i0] : 0;
    int d1 = (i0 + 1 < N_NODES) ? deg[i0 + 1] : 0;
    int p = d0 + d1;
    part[t] = p;
    __syncthreads();
    for (int off = 1; off < 256; off <<= 1) {
        int u = (t >= off) ? part[t - off] : 0;
        __syncthreads();
        part[t] += u;
        __syncthreads();
    }
    int base = blockoff[b] + part[t] - p;
    if (i0 < N_NODES)     { offs[i0] = base;           cursor[i0] = base; }
    if (i0 + 1 < N_NODES) { offs[i0 + 1] = base + d0;  cursor[i0 + 1] = base + d0; }
}

// ---------------------------------------------------------------------------
// fill3: group g=blockIdx&7 fills CSR srclist from its bucket's private
// segments (counts-guided, coalesced reads). cursor slice (50KB) + srclist
// slice (~1.6MB) stay in one XCD's L2.
// ---------------------------------------------------------------------------
__global__ __launch_bounds__(256) void fill3_kernel(const uint2* __restrict__ staging1,
                                                    const int* __restrict__ counts,
                                                    int* __restrict__ cursor,
                                                    int* __restrict__ srclist) {
    const int g  = blockIdx.x & (CGRP - 1);
    const int gb = blockIdx.x >> 3;
    const int nb = gridDim.x >> 3;
    for (int r = gb; r < BIN_BLOCKS; r += nb) {
        const int cnt = counts[r * CGRP + g];
        const uint2* sg = staging1 + ((size_t)(r * CGRP + g)) * CAPB;
        for (int i = threadIdx.x; i < cnt; i += 256) {
            uint2 v = sg[i];
            int p = atomicAdd(&cursor[v.x], 1);
            srclist[p] = (int)v.y;
        }
    }
}

// ---------------------------------------------------------------------------
// Gather aggregation over bf16 rows (round-8 proven): one wave per node.
// ---------------------------------------------------------------------------
__global__ __launch_bounds__(256) void gather_bf_kernel(
    const unsigned short* __restrict__ x_bf,
    const int* __restrict__ offs,
    const int* __restrict__ srclist,
    unsigned short* __restrict__ agg_bf) {
    int wave = (blockIdx.x * blockDim.x + threadIdx.x) >> 6;
    int lane = threadIdx.x & 63;
    if (wave >= N_NODES) return;
    int beg = offs[wave];
    int end = offs[wave + 1];
    float acc = 0.f;
    int j = beg;
    for (; j + 4 <= end; j += 4) {
        int s0 = srclist[j + 0];
        int s1 = srclist[j + 1];
        int s2 = srclist[j + 2];
        int s3 = srclist[j + 3];
        unsigned short v0 = x_bf[(size_t)s0 * 64 + lane];
        unsigned short v1 = x_bf[(size_t)s1 * 64 + lane];
        unsigned short v2 = x_bf[(size_t)s2 * 64 + lane];
        unsigned short v3 = x_bf[(size_t)s3 * 64 + lane];
        acc += bf2f(v0); acc += bf2f(v1); acc += bf2f(v2); acc += bf2f(v3);
    }
    for (; j < end; ++j) acc += bf2f(x_bf[(size_t)srclist[j] * 64 + lane]);
    agg_bf[(size_t)wave * 64 + lane] = f2bf(acc);
}

// ---------------------------------------------------------------------------
// MFMA transform (round-8 proven): out[n][c] = relu(agg.Wrel + x.Wroot + b)
// A: kk=0,1 from agg_bf, kk=2,3 from x_bf. m89-verified fragment layouts.
// ---------------------------------------------------------------------------
__global__ __launch_bounds__(256, 2) void transform_mfma_kernel(
    const unsigned short* __restrict__ agg_bf,  // [N][64] bf16
    const unsigned short* __restrict__ x_bf,    // [N][64] bf16
    const unsigned short* __restrict__ Wcat,    // [64][128] bf16
    const float* __restrict__ b_rel,
    float* __restrict__ out) {
    const int lane = threadIdx.x & 63;
    const int lr = lane & 15;
    const int lh = lane >> 4;

    bf16x8 bfr[4][4];
    #pragma unroll
    for (int cg = 0; cg < 4; ++cg)
        #pragma unroll
        for (int kk = 0; kk < 4; ++kk)
            bfr[cg][kk] = *(const bf16x8*)(Wcat + (cg * 16 + lr) * 128 + kk * 32 + lh * 8);

    float bias[4];
    #pragma unroll
    for (int cg = 0; cg < 4; ++cg) bias[cg] = b_rel[cg * 16 + lr];

    int wid = (blockIdx.x * blockDim.x + threadIdx.x) >> 6;
    int nw  = (gridDim.x * blockDim.x) >> 6;

    for (int g = wid; g < NGROUPS; g += nw) {
        const unsigned short* Aa = agg_bf + (size_t)(g * 16 + lr) * 64;
        const unsigned short* Ax = x_bf   + (size_t)(g * 16 + lr) * 64;
        bf16x8 afr[4];
        #pragma unroll
        for (int kk = 0; kk < 2; ++kk) {
            afr[kk]     = *(const bf16x8*)(Aa + kk * 32 + lh * 8);
            afr[kk + 2] = *(const bf16x8*)(Ax + kk * 32 + lh * 8);
        }
        #pragma unroll
        for (int cg = 0; cg < 4; ++cg) {
            f32x4 acc = {0.f, 0.f, 0.f, 0.f};
            #pragma unroll
            for (int kk = 0; kk < 4; ++kk)
                acc = __builtin_amdgcn_mfma_f32_16x16x32_bf16(afr[kk], bfr[cg][kk], acc, 0, 0, 0);
            #pragma unroll
            for (int r = 0; r < 4; ++r)
                out[(size_t)(g * 16 + lh * 4 + r) * 64 + cg * 16 + lr] =
                    fmaxf(acc[r] + bias[cg], 0.f);
        }
    }
}

// ---------------------------------------------------------------------------
// Fallback path (needs no workspace): atomic scatter + fp32 transform
// ---------------------------------------------------------------------------
__global__ void zero_kernel(float4* __restrict__ p, int n4) {
    int i = blockIdx.x * blockDim.x + threadIdx.x;
    int stride = gridDim.x * blockDim.x;
    for (; i < n4; i += stride) p[i] = make_float4(0.f, 0.f, 0.f, 0.f);
}

__global__ void scatter_kernel(const float4* __restrict__ x4,
                               const int* __restrict__ src,
                               const int* __restrict__ dst,
                               float* __restrict__ agg) {
    int idx = blockIdx.x * blockDim.x + threadIdx.x;
    const int total = N_EDGES * 16;
    int stride = gridDim.x * blockDim.x;
    for (; idx < total; idx += stride) {
        int e = idx >> 4;
        int q = idx & 15;
        int s = src[e];
        int d = dst[e];
        float4 v = x4[s * 16 + q];
        float* base = agg + d * 64 + q * 4;
        unsafeAtomicAdd(base + 0, v.x);
        unsafeAtomicAdd(base + 1, v.y);
        unsafeAtomicAdd(base + 2, v.z);
        unsafeAtomicAdd(base + 3, v.w);
    }
}

__global__ __launch_bounds__(256, 1) void transform3_kernel(
    const float* __restrict__ x,
    const float* __restrict__ W_rel,
    const float* __restrict__ b_rel,
    const float* __restrict__ W_root,
    float* __restrict__ agg_out) {
    const int lane = threadIdx.x & 63;
    float4 wr[16], wo[16];
    const float4* Wr4 = (const float4*)W_rel;
    const float4* Wo4 = (const float4*)W_root;
    #pragma unroll
    for (int i = 0; i < 16; ++i) {
        float4 a = Wr4[lane * 16 + i];
        float4 b = Wo4[lane * 16 + i];
        asm volatile("" : "+v"(a.x), "+v"(a.y), "+v"(a.z), "+v"(a.w));
        asm volatile("" : "+v"(b.x), "+v"(b.y), "+v"(b.z), "+v"(b.w));
        wr[i] = a;
        wo[i] = b;
    }
    const float bias = b_rel[lane];
    int gwave = (blockIdx.x * blockDim.x + threadIdx.x) >> 6;
    int nwaves = (gridDim.x * blockDim.x) >> 6;
    for (int node = gwave; node < N_NODES; node += nwaves) {
        const float4* ar4 = (const float4*)(agg_out + (size_t)node * 64);
        const float4* xr4 = (const float4*)(x + (size_t)node * 64);
        float acc = bias;
        #pragma unroll
        for (int i = 0; i < 16; ++i) {
            float4 a = ar4[i];
            float4 v = xr4[i];
            acc += a.x * wr[i].x + a.y * wr[i].y + a.z * wr[i].z + a.w * wr[i].w;
            acc += v.x * wo[i].x + v.y * wo[i].y + v.z * wo[i].z + v.w * wo[i].w;
        }
        agg_out[(size_t)node * 64 + lane] = fmaxf(acc, 0.f);
    }
}

extern "C" void kernel_launch(void* const* d_in, const int* in_sizes, int n_in,
                              void* d_out, int out_size, void* d_ws, size_t ws_size,
                              hipStream_t stream) {
    const float* x      = (const float*)d_in[0];
    const int*   adj    = (const int*)d_in[1];   // delivered as int32 [2][N_EDGES]
    const float* W_rel  = (const float*)d_in[2];
    const float* b_rel  = (const float*)d_in[3];
    const float* W_root = (const float*)d_in[4];
    float*       out    = (float*)d_out;

    const int* src = adj;
    const int* dst = adj + N_EDGES;

    // workspace layout (ints first, then bf16):
    //   counts[CPAD] | deg[NPAD] | offs[NPAD] | cursor[NPAD]
    //   | blocksum[BPAD] | blockoff[BPAD] | srclist[N_EDGES]
    //   | x_bf | agg_bf | Wcat   (bf16)
    // staging1 (1250 blk x 8 buckets x 256 uint2 = 20.5MB) lives in d_out
    // (25.6MB), fully consumed by fill3 BEFORE transform writes d_out.
    const size_t CPAD = 10048;                  // >= BIN_BLOCKS*CGRP (10000)
    const size_t NPAD = 100032;                 // >= N_NODES+1, multiple of 64
    const size_t BPAD = 256;
    const size_t n_ints = CPAD + 3 * NPAD + 2 * BPAD + (size_t)N_EDGES;
    const size_t row_elems = (size_t)N_NODES * 64;
    const size_t bf_base = ((n_ints * sizeof(int)) + 127) & ~(size_t)127;
    const size_t ws_needed = bf_base +
        (2 * row_elems + (size_t)NCLASS * 128) * sizeof(unsigned short);

    if (ws_size >= ws_needed) {
        int* counts   = (int*)d_ws;
        int* deg      = counts + CPAD;
        int* offs     = deg + NPAD;
        int* cursor   = offs + NPAD;
        int* blocksum = cursor + NPAD;
        int* blockoff = blocksum + BPAD;
        int* srclist  = blockoff + BPAD;
        unsigned short* x_bf   = (unsigned short*)((char*)d_ws + bf_base);
        unsigned short* agg_bf = x_bf + row_elems;
        unsigned short* Wcat   = agg_bf + row_elems;
        uint2* staging1 = (uint2*)d_out;

        zero_int_kernel<<<128, 256, 0, stream>>>(deg, N_NODES);
        prep_kernel<<<2048, 256, 0, stream>>>((const float4*)x, (ushort4*)x_bf,
                                              W_rel, W_root, Wcat);
        bin1_kernel<<<BIN_BLOCKS, 256, 0, stream>>>(src, dst, deg, counts, staging1);
        scan1_kernel<<<SCAN_NBLK, 256, 0, stream>>>(deg, blocksum);
        scan2_kernel<<<1, 256, 0, stream>>>(blocksum, blockoff, offs);
        scan3_kernel<<<SCAN_NBLK, 256, 0, stream>>>(deg, blockoff, offs, cursor);
        fill3_kernel<<<2048, 256, 0, stream>>>(staging1, counts, cursor, srclist);
        gather_bf_kernel<<<(N_NODES * 64 + 255) / 256, 256, 0, stream>>>(x_bf, offs, srclist, agg_bf);
        transform_mfma_kernel<<<1024, 256, 0, stream>>>(agg_bf, x_bf, Wcat, b_rel, out);
    } else {
        zero_kernel<<<2048, 256, 0, stream>>>((float4*)out, (N_NODES * NFEAT) / 4);
        scatter_kernel<<<4096, 256, 0, stream>>>((const float4*)x, src, dst, out);
        transform3_kernel<<<1024, 256, 0, stream>>>(x, W_rel, b_rel, W_root, out);
    }
}

// Round 13
// 91.509 us; speedup vs baseline: 8.7833x; 2.5501x over previous
//
#include <hip/hip_runtime.h>

#define N_NODES 100000
#define N_EDGES 1600000
#define NFEAT 64
#define NCLASS 64
#define NGROUPS (N_NODES / 16)   // 6250 16-node MFMA groups, exact

// fine parts: 511 parts x 196 nodes (510*196=99960 < 100000 <= 511*196)
#define PARTS 511
#define NPP 196
// bin: 256 blocks, each owns 6250 edges + private staging[PARTS][BCAP]
#define BINB 256
#define EPB (N_EDGES / BINB)     // 6250, exact
#define BCAP 48                  // per (block,part): mean 12.2, +10 sigma
#define TCAP 3712                // per part total: mean 3136, +10 sigma

typedef __attribute__((ext_vector_type(8))) short bf16x8;   // 8 bf16 = 4 VGPRs
typedef __attribute__((ext_vector_type(4))) float f32x4;

__device__ inline unsigned short f2bf(float f) {   // round-to-nearest-even
    union { float f; unsigned u; } v; v.f = f;
    unsigned u = v.u + 0x7fffu + ((v.u >> 16) & 1u);
    return (unsigned short)(u >> 16);
}
__device__ inline float bf2f(unsigned short s) {
    union { unsigned u; float f; } v; v.u = ((unsigned)s) << 16;
    return v.f;
}

// ---------------------------------------------------------------------------
// prep: x -> bf16 cast (vectorized) + Wcat bf16 concat, one launch.
// ---------------------------------------------------------------------------
#define X_ITEMS (N_NODES * NFEAT / 4)          // 1,600,000 float4->ushort4
#define W_ITEMS (NCLASS * 128)                 // 8,192 scalar
__global__ void prep_kernel(const float4* __restrict__ x4,
                            ushort4* __restrict__ xb4,
                            const float* __restrict__ W_rel,
                            const float* __restrict__ W_root,
                            unsigned short* __restrict__ Wcat) {
    int i = blockIdx.x * blockDim.x + threadIdx.x;
    int stride = gridDim.x * blockDim.x;
    for (; i < X_ITEMS + W_ITEMS; i += stride) {
        if (i < X_ITEMS) {
            float4 v = x4[i];
            ushort4 o;
            o.x = f2bf(v.x); o.y = f2bf(v.y); o.z = f2bf(v.z); o.w = f2bf(v.w);
            xb4[i] = o;
        } else {
            int j = i - X_ITEMS;
            int c = j >> 7, k = j & 127;
            float v = (k < 64) ? W_rel[c * 64 + k] : W_root[c * 64 + (k - 64)];
            Wcat[j] = f2bf(v);
        }
    }
}

// ---------------------------------------------------------------------------
// binfine: each block owns 6250 edges + a PRIVATE staging region
// [PARTS][BCAP]. LDS cursors only -> ZERO global atomics (round-12 lesson:
// the CSR's deg-atomics + cursor-allocated srclist pinned two kernels at the
// ~1 TB/s scattered-write ceiling). Entry = (dlocal<<17 | src), 4B.
// ---------------------------------------------------------------------------
__global__ __launch_bounds__(256) void binfine_kernel(const int* __restrict__ src,
                                                      const int* __restrict__ dst,
                                                      int* __restrict__ counts,
                                                      unsigned* __restrict__ staging) {
    __shared__ int cur[PARTS];
    const int blk = blockIdx.x;
    const int tid = threadIdx.x;
    for (int i = tid; i < PARTS; i += 256) cur[i] = 0;
    __syncthreads();
    const int e0 = blk * EPB;
    for (int r = tid; r < EPB; r += 256) {
        int e = e0 + r;
        unsigned d = (unsigned)dst[e];           // coalesced
        unsigned s = (unsigned)src[e];           // coalesced
        unsigned p = d / (unsigned)NPP;          // magic-mul
        unsigned dl = d - p * (unsigned)NPP;
        int pos = atomicAdd(&cur[p], 1);         // LDS, mean contention ~0.5
        if (pos < BCAP)
            staging[((size_t)blk * PARTS + p) * BCAP + pos] = (dl << 17) | s;
    }
    __syncthreads();
    for (int i = tid; i < PARTS; i += 256)
        counts[blk * PARTS + i] = min(cur[i], BCAP);   // coalesced, no zero-pass needed
}

// ---------------------------------------------------------------------------
// aggsort: one 1024-thread block per fine part.
//  1. segment-prefix over the 256 per-block counts (LDS Hillis-Steele)
//  2. cooperative copy of all segments into a dense LDS list
//  3. counting sort by dlocal (196 LDS counters + scatter)
//  4. per-node wave gather: lane=feature, fp32 accumulate, write agg_bf row
// Replaces {deg-hist, scan x3, fill, gather} with zero global scatter traffic.
// ---------------------------------------------------------------------------
__global__ __launch_bounds__(1024) void aggsort_kernel(
    const unsigned short* __restrict__ x_bf,
    const int* __restrict__ counts,
    const unsigned* __restrict__ staging,
    unsigned short* __restrict__ agg_bf) {
    __shared__ unsigned list[TCAP];
    __shared__ unsigned slot[TCAP];
    __shared__ int segorig[BINB], segscan[BINB], segoff[BINB];
    __shared__ int cnt[NPP], nodeoff[NPP], curn[NPP];
    __shared__ int scan256[256];

    const int p = blockIdx.x;
    const int tid = threadIdx.x;

    // 1. per-segment counts + inclusive scan over 256
    if (tid < BINB) {
        int c = counts[tid * PARTS + p];
        segorig[tid] = c;
        segscan[tid] = c;
    }
    __syncthreads();
    for (int off = 1; off < BINB; off <<= 1) {
        int v = 0;
        if (tid < BINB && tid >= off) v = segscan[tid - off];
        __syncthreads();
        if (tid < BINB && tid >= off) segscan[tid] += v;
        __syncthreads();
    }
    if (tid < BINB) segoff[tid] = segscan[tid] - segorig[tid];  // exclusive
    __syncthreads();
    const int total = min(segscan[BINB - 1], TCAP);

    // 2. cooperative copy: flatten (seg, idx) over 256*BCAP
    for (int k = tid; k < BINB * BCAP; k += 1024) {
        int seg = k / BCAP;
        int idx = k - seg * BCAP;
        if (idx < segorig[seg]) {
            int dp = segoff[seg] + idx;
            if (dp < TCAP)
                list[dp] = staging[((size_t)seg * PARTS + p) * BCAP + idx];
        }
    }
    // 3a. zero node counters
    for (int i = tid; i < NPP; i += 1024) cnt[i] = 0;
    __syncthreads();
    for (int i = tid; i < total; i += 1024)
        atomicAdd(&cnt[list[i] >> 17], 1);
    __syncthreads();
    // 3b. inclusive scan over 196 (padded to 256)
    if (tid < 256) scan256[tid] = (tid < NPP) ? cnt[tid] : 0;
    __syncthreads();
    for (int off = 1; off < 256; off <<= 1) {
        int v = 0;
        if (tid < 256 && tid >= off) v = scan256[tid - off];
        __syncthreads();
        if (tid < 256 && tid >= off) scan256[tid] += v;
        __syncthreads();
    }
    if (tid < NPP) {
        int st = scan256[tid] - cnt[tid];   // exclusive
        nodeoff[tid] = st;
        curn[tid] = st;
    }
    __syncthreads();
    // 3c. scatter into sorted order (keep only src, 17 bits)
    for (int i = tid; i < total; i += 1024) {
        unsigned v = list[i];
        int r = (int)(v >> 17);
        int pos = atomicAdd(&curn[r], 1);
        slot[pos] = v & 0x1FFFFu;
    }
    __syncthreads();
    // 4. per-node wave gather
    const int lane = tid & 63;
    const int w = tid >> 6;            // 0..15
    for (int r = w; r < NPP; r += 16) {
        int node = p * NPP + r;
        if (node >= N_NODES) break;    // wave-uniform
        int beg = nodeoff[r];
        int end = beg + cnt[r];
        float acc = 0.f;
        int j = beg;
        for (; j + 4 <= end; j += 4) {   // 4 independent row loads in flight
            int s0 = (int)slot[j + 0];
            int s1 = (int)slot[j + 1];
            int s2 = (int)slot[j + 2];
            int s3 = (int)slot[j + 3];
            float v0 = bf2f(x_bf[(size_t)s0 * 64 + lane]);
            float v1 = bf2f(x_bf[(size_t)s1 * 64 + lane]);
            float v2 = bf2f(x_bf[(size_t)s2 * 64 + lane]);
            float v3 = bf2f(x_bf[(size_t)s3 * 64 + lane]);
            acc += v0; acc += v1; acc += v2; acc += v3;
        }
        for (; j < end; ++j) acc += bf2f(x_bf[(size_t)slot[j] * 64 + lane]);
        agg_bf[(size_t)node * 64 + lane] = f2bf(acc);
    }
}

// ---------------------------------------------------------------------------
// MFMA transform (round-8 proven): out[n][c] = relu(agg.Wrel + x.Wroot + b)
// A: kk=0,1 from agg_bf, kk=2,3 from x_bf. m89-verified fragment layouts.
// ---------------------------------------------------------------------------
__global__ __launch_bounds__(256, 2) void transform_mfma_kernel(
    const unsigned short* __restrict__ agg_bf,  // [N][64] bf16
    const unsigned short* __restrict__ x_bf,    // [N][64] bf16
    const unsigned short* __restrict__ Wcat,    // [64][128] bf16
    const float* __restrict__ b_rel,
    float* __restrict__ out) {
    const int lane = threadIdx.x & 63;
    const int lr = lane & 15;
    const int lh = lane >> 4;

    bf16x8 bfr[4][4];
    #pragma unroll
    for (int cg = 0; cg < 4; ++cg)
        #pragma unroll
        for (int kk = 0; kk < 4; ++kk)
            bfr[cg][kk] = *(const bf16x8*)(Wcat + (cg * 16 + lr) * 128 + kk * 32 + lh * 8);

    float bias[4];
    #pragma unroll
    for (int cg = 0; cg < 4; ++cg) bias[cg] = b_rel[cg * 16 + lr];

    int wid = (blockIdx.x * blockDim.x + threadIdx.x) >> 6;
    int nw  = (gridDim.x * blockDim.x) >> 6;

    for (int g = wid; g < NGROUPS; g += nw) {
        const unsigned short* Aa = agg_bf + (size_t)(g * 16 + lr) * 64;
        const unsigned short* Ax = x_bf   + (size_t)(g * 16 + lr) * 64;
        bf16x8 afr[4];
        #pragma unroll
        for (int kk = 0; kk < 2; ++kk) {
            afr[kk]     = *(const bf16x8*)(Aa + kk * 32 + lh * 8);
            afr[kk + 2] = *(const bf16x8*)(Ax + kk * 32 + lh * 8);
        }
        #pragma unroll
        for (int cg = 0; cg < 4; ++cg) {
            f32x4 acc = {0.f, 0.f, 0.f, 0.f};
            #pragma unroll
            for (int kk = 0; kk < 4; ++kk)
                acc = __builtin_amdgcn_mfma_f32_16x16x32_bf16(afr[kk], bfr[cg][kk], acc, 0, 0, 0);
            #pragma unroll
            for (int r = 0; r < 4; ++r)
                out[(size_t)(g * 16 + lh * 4 + r) * 64 + cg * 16 + lr] =
                    fmaxf(acc[r] + bias[cg], 0.f);
        }
    }
}

// ---------------------------------------------------------------------------
// Fallback path (needs no workspace): atomic scatter + fp32 transform
// ---------------------------------------------------------------------------
__global__ void zero_kernel(float4* __restrict__ p, int n4) {
    int i = blockIdx.x * blockDim.x + threadIdx.x;
    int stride = gridDim.x * blockDim.x;
    for (; i < n4; i += stride) p[i] = make_float4(0.f, 0.f, 0.f, 0.f);
}

__global__ void scatter_kernel(const float4* __restrict__ x4,
                               const int* __restrict__ src,
                               const int* __restrict__ dst,
                               float* __restrict__ agg) {
    int idx = blockIdx.x * blockDim.x + threadIdx.x;
    const int total = N_EDGES * 16;
    int stride = gridDim.x * blockDim.x;
    for (; idx < total; idx += stride) {
        int e = idx >> 4;
        int q = idx & 15;
        int s = src[e];
        int d = dst[e];
        float4 v = x4[s * 16 + q];
        float* base = agg + d * 64 + q * 4;
        unsafeAtomicAdd(base + 0, v.x);
        unsafeAtomicAdd(base + 1, v.y);
        unsafeAtomicAdd(base + 2, v.z);
        unsafeAtomicAdd(base + 3, v.w);
    }
}

__global__ __launch_bounds__(256, 1) void transform3_kernel(
    const float* __restrict__ x,
    const float* __restrict__ W_rel,
    const float* __restrict__ b_rel,
    const float* __restrict__ W_root,
    float* __restrict__ agg_out) {
    const int lane = threadIdx.x & 63;
    float4 wr[16], wo[16];
    const float4* Wr4 = (const float4*)W_rel;
    const float4* Wo4 = (const float4*)W_root;
    #pragma unroll
    for (int i = 0; i < 16; ++i) {
        float4 a = Wr4[lane * 16 + i];
        float4 b = Wo4[lane * 16 + i];
        asm volatile("" : "+v"(a.x), "+v"(a.y), "+v"(a.z), "+v"(a.w));
        asm volatile("" : "+v"(b.x), "+v"(b.y), "+v"(b.z), "+v"(b.w));
        wr[i] = a;
        wo[i] = b;
    }
    const float bias = b_rel[lane];
    int gwave = (blockIdx.x * blockDim.x + threadIdx.x) >> 6;
    int nwaves = (gridDim.x * blockDim.x) >> 6;
    for (int node = gwave; node < N_NODES; node += nwaves) {
        const float4* ar4 = (const float4*)(agg_out + (size_t)node * 64);
        const float4* xr4 = (const float4*)(x + (size_t)node * 64);
        float acc = bias;
        #pragma unroll
        for (int i = 0; i < 16; ++i) {
            float4 a = ar4[i];
            float4 v = xr4[i];
            acc += a.x * wr[i].x + a.y * wr[i].y + a.z * wr[i].z + a.w * wr[i].w;
            acc += v.x * wo[i].x + v.y * wo[i].y + v.z * wo[i].z + v.w * wo[i].w;
        }
        agg_out[(size_t)node * 64 + lane] = fmaxf(acc, 0.f);
    }
}

extern "C" void kernel_launch(void* const* d_in, const int* in_sizes, int n_in,
                              void* d_out, int out_size, void* d_ws, size_t ws_size,
                              hipStream_t stream) {
    const float* x      = (const float*)d_in[0];
    const int*   adj    = (const int*)d_in[1];   // delivered as int32 [2][N_EDGES]
    const float* W_rel  = (const float*)d_in[2];
    const float* b_rel  = (const float*)d_in[3];
    const float* W_root = (const float*)d_in[4];
    float*       out    = (float*)d_out;

    const int* src = adj;
    const int* dst = adj + N_EDGES;

    // workspace: counts[BINB*PARTS] ints | x_bf | agg_bf | Wcat (bf16)
    // staging (256 blk x 511 parts x 48 x 4B = 25.1MB) lives in d_out
    // (25.6MB), fully consumed by aggsort BEFORE transform writes d_out.
    const size_t CNT_INTS = (size_t)BINB * PARTS;          // 130,816
    const size_t row_elems = (size_t)N_NODES * 64;
    const size_t bf_base = ((CNT_INTS * sizeof(int)) + 127) & ~(size_t)127;
    const size_t ws_needed = bf_base +
        (2 * row_elems + (size_t)NCLASS * 128) * sizeof(unsigned short);

    if (ws_size >= ws_needed) {
        int* counts = (int*)d_ws;
        unsigned short* x_bf   = (unsigned short*)((char*)d_ws + bf_base);
        unsigned short* agg_bf = x_bf + row_elems;
        unsigned short* Wcat   = agg_bf + row_elems;
        unsigned* staging = (unsigned*)d_out;

        prep_kernel<<<2048, 256, 0, stream>>>((const float4*)x, (ushort4*)x_bf,
                                              W_rel, W_root, Wcat);
        binfine_kernel<<<BINB, 256, 0, stream>>>(src, dst, counts, staging);
        aggsort_kernel<<<PARTS, 1024, 0, stream>>>(x_bf, counts, staging, agg_bf);
        transform_mfma_kernel<<<1024, 256, 0, stream>>>(agg_bf, x_bf, Wcat, b_rel, out);
    } else {
        zero_kernel<<<2048, 256, 0, stream>>>((float4*)out, (N_NODES * NFEAT) / 4);
        scatter_kernel<<<4096, 256, 0, stream>>>((const float4*)x, src, dst, out);
        transform3_kernel<<<1024, 256, 0, stream>>>(x, W_rel, b_rel, W_root, out);
    }
}